// Round 16
// baseline (481.118 us; speedup 1.0000x reference)
//
#include <hip/hip_runtime.h>
#include <hip/hip_bf16.h>

#define Sq 2048
#define Dm 2048
#define HDim 3072
#define QKVDim 9216
#define NH 24
#define DH 128
#define FF 8192
#define ATT_SCALE 0.08838834764831845f
#define ATT_SCALE2 0.12752534331809017f   // ATT_SCALE * log2(e)

using bf16 = __hip_bfloat16;
typedef __attribute__((ext_vector_type(8))) short bf16x8;
typedef __attribute__((ext_vector_type(4))) float f32x4;
typedef unsigned int u32;
typedef unsigned long long u64;
typedef __attribute__((ext_vector_type(4))) u32 u32x4;

__device__ __forceinline__ void gload_lds16(const void* g, void* l) {
    __builtin_amdgcn_global_load_lds(
        (const __attribute__((address_space(1))) void*)g,
        (__attribute__((address_space(3))) void*)l, 16, 0, 0);
}

// ---------------- merged: LayerNorm+RMSNorm rows  |  QKV weight transpose ------
// blocks [0,Sq): LN row;  blocks [Sq, Sq+3*1536): 64x64 transpose tiles of Wq/Wk/Wv
__global__ __launch_bounds__(256) void ln_qkvt_kernel(
    const float* __restrict__ x, const float* __restrict__ g, const float* __restrict__ b,
    const float* __restrict__ ag, float* __restrict__ xnf, bf16* __restrict__ h,
    const float* __restrict__ Wq, const float* __restrict__ Wk, const float* __restrict__ Wv,
    bf16* __restrict__ Wt)
{
    union SmemU {
        float red[12];
        float tile[64][65];
    };
    __shared__ SmemU sm;
    int bid = blockIdx.x;
    int t = threadIdx.x;

    if (bid >= Sq) {
        // ---- transpose path: W[Dm][HDim] -> Wt[HDim][Dm] (per matrix z) ----
        int tb = bid - Sq;
        int z = tb / 1536, rr = tb % 1536;
        int bx = rr % 48, by = rr / 48;              // bx over HDim, by over Dm
        const float* W = z == 0 ? Wq : (z == 1 ? Wk : Wv);
        bf16* dst = Wt + (size_t)z * HDim * Dm;
        int n0 = bx * 64, k0 = by * 64;
        int lr = t >> 4, lc = (t & 15) * 4;
#pragma unroll
        for (int i = 0; i < 4; i++) {
            int r = lr + i * 16;
            f32x4 v = *reinterpret_cast<const f32x4*>(W + (size_t)(k0 + r) * HDim + n0 + lc);
            *reinterpret_cast<f32x4*>(&sm.tile[r][lc]) = v;
        }
        __syncthreads();
        int nr = t >> 3, kc = (t & 7) * 8;
#pragma unroll
        for (int i = 0; i < 2; i++) {
            int n = nr + i * 32;
            bf16 o8[8];
#pragma unroll
            for (int j = 0; j < 8; j++) o8[j] = __float2bfloat16(sm.tile[kc + j][n]);
            *reinterpret_cast<u32x4*>(dst + (size_t)(n0 + n) * Dm + k0 + kc) =
                *reinterpret_cast<const u32x4*>(o8);
        }
        return;
    }

    // ---- LN path ----
    int row = bid;
    int lane = t & 63, wid = t >> 6;
    const float* xr = x + (size_t)row * Dm;

    float v[8];
    float sum = 0.f, ssq = 0.f;
#pragma unroll
    for (int i = 0; i < 8; i++) {
        float f = xr[t + 256 * i];
        v[i] = f; sum += f; ssq += f * f;
    }
#pragma unroll
    for (int off = 32; off > 0; off >>= 1) {
        sum += __shfl_down(sum, off);
        ssq += __shfl_down(ssq, off);
    }
    if (lane == 0) { sm.red[wid] = sum; sm.red[4 + wid] = ssq; }
    __syncthreads();
    sum = sm.red[0] + sm.red[1] + sm.red[2] + sm.red[3];
    ssq = sm.red[4] + sm.red[5] + sm.red[6] + sm.red[7];
    float mu = sum * (1.f / Dm);
    float var = ssq * (1.f / Dm) - mu * mu;
    float rstd = rsqrtf(var + 1e-5f);

    float xn[8];
    float s2 = 0.f;
#pragma unroll
    for (int i = 0; i < 8; i++) {
        int col = t + 256 * i;
        float xv = (v[i] - mu) * rstd * g[col] + b[col];
        xn[i] = xv;
        xnf[(size_t)row * Dm + col] = xv;
        s2 += xv * xv;
    }
#pragma unroll
    for (int off = 32; off > 0; off >>= 1) s2 += __shfl_down(s2, off);
    if (lane == 0) sm.red[8 + wid] = s2;
    __syncthreads();
    s2 = sm.red[8] + sm.red[9] + sm.red[10] + sm.red[11];
    float rms = rsqrtf(s2 * (1.f / Dm) + 1e-5f);
#pragma unroll
    for (int i = 0; i < 8; i++) {
        int col = t + 256 * i;
        h[(size_t)row * Dm + col] = __float2bfloat16(xn[i] * rms * ag[col]);
    }
}

// ---------------- transpose + fp32->bf16 convert: W[K][N] -> Wt[N][K] ----------------
// 64x64 tile, 256 threads (standalone, for W1/W2)
__global__ __launch_bounds__(256) void transpose_cvt_kernel(
    const float* __restrict__ W, bf16* __restrict__ Wt, int K, int N)
{
    __shared__ float tile[64][65];
    int n0 = blockIdx.x * 64, k0 = blockIdx.y * 64;
    int t = threadIdx.x;
    int lr = t >> 4, lc = (t & 15) * 4;
#pragma unroll
    for (int i = 0; i < 4; i++) {
        int r = lr + i * 16;
        f32x4 v = *reinterpret_cast<const f32x4*>(W + (size_t)(k0 + r) * N + n0 + lc);
        *reinterpret_cast<f32x4*>(&tile[r][lc]) = v;
    }
    __syncthreads();
    int nr = t >> 3, kc = (t & 7) * 8;
#pragma unroll
    for (int i = 0; i < 2; i++) {
        int n = nr + i * 32;
        bf16 o8[8];
#pragma unroll
        for (int j = 0; j < 8; j++) o8[j] = __float2bfloat16(tile[kc + j][n]);
        *reinterpret_cast<u32x4*>(Wt + (size_t)(n0 + n) * K + k0 + kc) =
            *reinterpret_cast<const u32x4*>(o8);
    }
}

// ---------------- fused: hb = bf16(xnf); out = xnf + b2 ----------------
__global__ __launch_bounds__(256) void cvt_prefill_kernel(
    const float* __restrict__ xnf, const float* __restrict__ bias,
    bf16* __restrict__ hb, float* __restrict__ o, int N)
{
    int i = (blockIdx.x * 256 + threadIdx.x) * 8;
    int col = i % N;
    f32x4 a = *reinterpret_cast<const f32x4*>(xnf + i);
    f32x4 b = *reinterpret_cast<const f32x4*>(xnf + i + 4);
    bf16 r[8];
#pragma unroll
    for (int j = 0; j < 4; j++) { r[j] = __float2bfloat16(a[j]); r[4 + j] = __float2bfloat16(b[j]); }
    *reinterpret_cast<u32x4*>(hb + i) = *reinterpret_cast<const u32x4*>(r);
    f32x4 b0 = *reinterpret_cast<const f32x4*>(bias + col);
    f32x4 b1v = *reinterpret_cast<const f32x4*>(bias + col + 4);
    f32x4 o0 = {a[0] + b0[0], a[1] + b0[1], a[2] + b0[2], a[3] + b0[3]};
    f32x4 o1 = {b[0] + b1v[0], b[1] + b1v[1], b[2] + b1v[2], b[3] + b1v[3]};
    *reinterpret_cast<f32x4*>(o + i) = o0;
    *reinterpret_cast<f32x4*>(o + i + 4) = o1;
}

// ---------------- 128x128 bf16 MFMA GEMM (m97 structure, BK=64, swizzled) ------
// EPI 0: Cb = bf16(acc);  EPI 2: Cb = bf16(gelu(acc+bias));  EPI 4: atomicAdd(Cf, acc)
template <int EPI>
__global__ __launch_bounds__(256, 4) void gemm_kernel(
    const bf16* __restrict__ A, const bf16* __restrict__ Bt,
    int M, int N, int K, int Ksplit,
    bf16* Cb, float* Cf, const float* __restrict__ bias)
{
    __shared__ __align__(16) bf16 As[128 * 64];
    __shared__ __align__(16) bf16 Bs[128 * 64];
    int m0 = blockIdx.y * 128, n0 = blockIdx.x * 128;
    int kbeg = blockIdx.z * Ksplit, kend = kbeg + Ksplit;
    int tid = threadIdx.x;
    int lane = tid & 63, w = tid >> 6;
    int wr = w >> 1, wc = w & 1;
    int l15 = lane & 15, lhi = lane >> 4;

    int srow = lane >> 3;
    int scol = ((lane & 7) ^ (lane >> 3)) * 8;

    const f32x4 zero4 = {0.f, 0.f, 0.f, 0.f};
    f32x4 acc[4][4];
#pragma unroll
    for (int m = 0; m < 4; m++)
#pragma unroll
        for (int n = 0; n < 4; n++) acc[m][n] = zero4;

    for (int k0 = kbeg; k0 < kend; k0 += 64) {
        __syncthreads();
#pragma unroll
        for (int c = 0; c < 4; c++) {
            int row = w * 32 + c * 8 + srow;
            gload_lds16(A + (size_t)(m0 + row) * K + k0 + scol,
                        (char*)As + w * 4096 + c * 1024);
            gload_lds16(Bt + (size_t)(n0 + row) * K + k0 + scol,
                        (char*)Bs + w * 4096 + c * 1024);
        }
        __syncthreads();
#pragma unroll
        for (int ks = 0; ks < 2; ks++) {
            bf16x8 af[4], bfr[4];
#pragma unroll
            for (int m = 0; m < 4; m++) {
                int r = wr * 64 + m * 16 + l15;
                af[m] = *reinterpret_cast<const bf16x8*>(
                    &As[r * 64 + (((ks << 2) + lhi) ^ (r & 7)) * 8]);
            }
#pragma unroll
            for (int n = 0; n < 4; n++) {
                int r = wc * 64 + n * 16 + l15;
                bfr[n] = *reinterpret_cast<const bf16x8*>(
                    &Bs[r * 64 + (((ks << 2) + lhi) ^ (r & 7)) * 8]);
            }
#pragma unroll
            for (int m = 0; m < 4; m++)
#pragma unroll
                for (int n = 0; n < 4; n++)
                    acc[m][n] = __builtin_amdgcn_mfma_f32_16x16x32_bf16(af[m], bfr[n], acc[m][n], 0, 0, 0);
        }
    }

#pragma unroll
    for (int m = 0; m < 4; m++) {
        int row = m0 + wr * 64 + m * 16 + lhi * 4;
#pragma unroll
        for (int n = 0; n < 4; n++) {
            int col = n0 + wc * 64 + n * 16 + l15;
#pragma unroll
            for (int j = 0; j < 4; j++) {
                float vv = acc[m][n][j];
                size_t idx = (size_t)(row + j) * N + col;
                if (EPI == 0) {
                    Cb[idx] = __float2bfloat16(vv);
                } else if (EPI == 2) {
                    float o = vv + bias[col];
                    float u = 1.5957691216057308f * (o + 0.044715f * o * o * o);
                    Cb[idx] = __float2bfloat16(o / (1.0f + __expf(-u)));
                } else {
                    atomicAdd(&Cf[idx], vv);
                }
            }
        }
    }
}

// ---------------- merged: flash attention (8-wave QBLK=128)  |  Wo transpose ----
// blocks [0, NH*Sq/128): attention; blocks beyond: 64x64 Wo transpose tiles
// (wbuf is dead during attention: QKV^T already consumed, Wo^T needed next).
__global__ __launch_bounds__(512) void attn_kernel(
    const bf16* __restrict__ qkv, bf16* __restrict__ o,
    const float* __restrict__ Wo, bf16* __restrict__ Wot)
{
    struct AttnSmem {
        bf16 KsF[2][64 * 128];
        bf16 VtF[128 * 72];
        bf16 Pl[8][16][76];
    };
    struct TransSmem { float tile[64][65]; };
    union SmemU { AttnSmem a; TransSmem tp; };
    __shared__ SmemU sm;

    int bid = blockIdx.x;
    int tid = threadIdx.x;
    const int NATT = NH * (Sq / 128);

    if (bid >= NATT) {
        // ---- Wo transpose: Wo[HDim][Dm] -> Wot[Dm][HDim], 512-thread 64x64 tile
        int tb = bid - NATT;                 // 0..1535
        int bx = tb & 31, by = tb >> 5;      // bx over Dm(32), by over HDim(48)
        int n0 = bx * 64, k0 = by * 64;
        int lr = tid >> 4, lc = (tid & 15) * 4;
#pragma unroll
        for (int i = 0; i < 2; i++) {
            int r = lr + i * 32;
            f32x4 v = *reinterpret_cast<const f32x4*>(Wo + (size_t)(k0 + r) * Dm + n0 + lc);
            *reinterpret_cast<f32x4*>(&sm.tp.tile[r][lc]) = v;
        }
        __syncthreads();
        int nr = tid >> 3, kc = (tid & 7) * 8;
        bf16 o8[8];
#pragma unroll
        for (int j = 0; j < 8; j++) o8[j] = __float2bfloat16(sm.tp.tile[kc + j][nr]);
        *reinterpret_cast<u32x4*>(Wot + (size_t)(n0 + nr) * HDim + k0 + kc) =
            *reinterpret_cast<const u32x4*>(o8);
        return;
    }

    int rank = bid;
    int qb = (Sq / 128 - 1) - rank / NH;   // heaviest first
    int head = rank % NH;
    const bf16* q = qkv + head * DH;
    const bf16* k = qkv + HDim + head * DH;
    const bf16* v = qkv + 2 * HDim + head * DH;
    int lane = tid & 63, w = tid >> 6;   // w 0..7
    int l15 = lane & 15, lhi = lane >> 4;
    int qrow0 = qb * 128 + w * 16;

    bf16x8 aq[4];
    const bf16* qbase = q + (size_t)(qrow0 + l15) * QKVDim;
#pragma unroll
    for (int kk = 0; kk < 4; kk++)
        aq[kk] = *reinterpret_cast<const bf16x8*>(qbase + kk * 32 + lhi * 8);

    bf16x8 vones;
#pragma unroll
    for (int j = 0; j < 8; j++) vones[j] = (short)0x3F80;

    int vkv = lhi * 2 + (w & 1) + (w >> 1) * 8;   // 0..31; +i*32
    int vd0 = l15 * 8;
    int vxr = l15 & 7;
    const bf16* vbase = v + (size_t)vkv * QKVDim + vd0;

    const f32x4 zero4 = {0.f, 0.f, 0.f, 0.f};
    f32x4 acc_o[8];
#pragma unroll
    for (int db = 0; db < 8; db++) acc_o[db] = zero4;
    f32x4 acc_l = zero4;
    float mrow[4];
#pragma unroll
    for (int r = 0; r < 4; r++) mrow[r] = -1e30f;

    int nt = 2 * qb + 2;

    // prologue: K(0) -> KsF[0] via DMA; V(0) -> VtF directly
    {
#pragma unroll
        for (int c = 0; c < 2; c++) {
            int row = w * 8 + c * 4 + lhi;
            int cb = l15 ^ (row & 7);
            gload_lds16(k + (size_t)row * QKVDim + cb * 8,
                        (char*)&sm.a.KsF[0][0] + w * 2048 + c * 1024);
        }
#pragma unroll
        for (int i = 0; i < 2; i++) {
            int kv = vkv + i * 32;
            bf16x8 vv = *reinterpret_cast<const bf16x8*>(vbase + (size_t)(i * 32) * QKVDim);
            int vb = kv >> 3, kr = kv & 7;
#pragma unroll
            for (int j = 0; j < 8; j++)
                sm.a.VtF[(vd0 + j) * 72 + ((vb ^ vxr) << 3) + kr] = ((const bf16*)&vv)[j];
        }
        __syncthreads();
    }

    for (int kb = 0; kb < nt; kb++) {
        int kv0 = kb * 64;
        int p = kb & 1;
        bf16x8 vreg[2];
        bool pref = (kb + 1 < nt);
        if (pref) {
            int nv0 = kv0 + 64;
#pragma unroll
            for (int c = 0; c < 2; c++) {
                int row = w * 8 + c * 4 + lhi;
                int cb = l15 ^ (row & 7);
                gload_lds16(k + (size_t)(nv0 + row) * QKVDim + cb * 8,
                            (char*)&sm.a.KsF[p ^ 1][0] + w * 2048 + c * 1024);
            }
#pragma unroll
            for (int i = 0; i < 2; i++)
                vreg[i] = *reinterpret_cast<const bf16x8*>(
                    vbase + (size_t)(nv0 + i * 32) * QKVDim);
        }

        bool active = (kv0 <= qrow0 + 15);   // wave-uniform causal skip
        if (active) {
            f32x4 sacc[4];
            __builtin_amdgcn_s_setprio(1);
#pragma unroll
            for (int nb = 0; nb < 4; nb++) {
                sacc[nb] = zero4;
                int krow = nb * 16 + l15;
#pragma unroll
                for (int kk = 0; kk < 4; kk++) {
                    const char* kp = (const char*)&sm.a.KsF[p][0] + krow * 256 +
                                     ((kk * 64 + lhi * 16) ^ ((krow & 7) << 4));
                    bf16x8 bk = *reinterpret_cast<const bf16x8*>(kp);
                    sacc[nb] = __builtin_amdgcn_mfma_f32_16x16x32_bf16(aq[kk], bk, sacc[nb], 0, 0, 0);
                }
            }
            __builtin_amdgcn_s_setprio(0);

            bool msk = (kv0 + 63 > qrow0);
            float sv[4][4];
            float pm[4];
#pragma unroll
            for (int r = 0; r < 4; r++) pm[r] = -1e30f;
#pragma unroll
            for (int nb = 0; nb < 4; nb++) {
                int kvc = kv0 + nb * 16 + l15;
#pragma unroll
                for (int r = 0; r < 4; r++) {
                    int qr = qrow0 + lhi * 4 + r;
                    float s = sacc[nb][r] * ATT_SCALE2;   // base-2 domain
                    if (msk && kvc > qr) s = -1e30f;
                    sv[nb][r] = s;
                    pm[r] = fmaxf(pm[r], s);
                }
            }
#pragma unroll
            for (int off = 1; off < 16; off <<= 1)
#pragma unroll
                for (int r = 0; r < 4; r++)
                    pm[r] = fmaxf(pm[r], __shfl_xor(pm[r], off));

            // defer-max (threshold 11.5 in log2 units ~ e^8 bound)
            float nm[4];
            bool need = false;
#pragma unroll
            for (int r = 0; r < 4; r++) {
                nm[r] = fmaxf(mrow[r], pm[r]);
                need = need || (pm[r] > mrow[r] + 11.5f);
            }
            if (__any(need)) {
#pragma unroll
                for (int r = 0; r < 4; r++) {
                    float sc = exp2f(mrow[r] - nm[r]);
                    mrow[r] = nm[r];
                    acc_l[r] *= sc;
#pragma unroll
                    for (int db = 0; db < 8; db++) acc_o[db][r] *= sc;
                }
            }

#pragma unroll
            for (int nb = 0; nb < 4; nb++)
#pragma unroll
                for (int r = 0; r < 4; r++)
                    sv[nb][r] = exp2f(sv[nb][r] - mrow[r]);

#pragma unroll
            for (int nb = 0; nb < 4; nb++)
#pragma unroll
                for (int r = 0; r < 4; r++)
                    sm.a.Pl[w][lhi * 4 + r][nb * 16 + l15] = __float2bfloat16(sv[nb][r]);

            __builtin_amdgcn_s_setprio(1);
#pragma unroll
            for (int ks = 0; ks < 2; ks++) {
                bf16x8 ap = *reinterpret_cast<const bf16x8*>(&sm.a.Pl[w][l15][ks * 32 + lhi * 8]);
                acc_l = __builtin_amdgcn_mfma_f32_16x16x32_bf16(ap, vones, acc_l, 0, 0, 0);
#pragma unroll
                for (int db = 0; db < 8; db++) {
                    int dv = db * 16 + l15;
                    int blk = (ks * 4 + lhi) ^ ((dv >> 3) & 7);
                    bf16x8 bv = *reinterpret_cast<const bf16x8*>(&sm.a.VtF[dv * 72 + blk * 8]);
                    acc_o[db] = __builtin_amdgcn_mfma_f32_16x16x32_bf16(ap, bv, acc_o[db], 0, 0, 0);
                }
            }
            __builtin_amdgcn_s_setprio(0);
        }

        __syncthreads();   // barrier1: all waves done reading VtF
        if (pref) {
#pragma unroll
            for (int i = 0; i < 2; i++) {
                int kv = vkv + i * 32;
                int vb = kv >> 3, kr = kv & 7;
#pragma unroll
                for (int j = 0; j < 8; j++)
                    sm.a.VtF[(vd0 + j) * 72 + ((vb ^ vxr) << 3) + kr] = ((const bf16*)&vreg[i])[j];
            }
        }
        __syncthreads();   // barrier2: V(kb+1) published; K(kb+1) DMA drained
    }

#pragma unroll
    for (int db = 0; db < 8; db++)
#pragma unroll
        for (int r = 0; r < 4; r++) {
            int qr = qrow0 + lhi * 4 + r;
            float val = acc_o[db][r] / acc_l[r];
            o[(size_t)qr * HDim + head * DH + db * 16 + l15] = __float2bfloat16(val);
        }
}

// ---------------- host launch ----------------
extern "C" void kernel_launch(void* const* d_in, const int* in_sizes, int n_in,
                              void* d_out, int out_size, void* d_ws, size_t ws_size,
                              hipStream_t stream)
{
    const float* x     = (const float*)d_in[0];
    const float* ln_g  = (const float*)d_in[1];
    const float* ln_b  = (const float*)d_in[2];
    const float* attng = (const float*)d_in[3];
    const float* Wq    = (const float*)d_in[4];
    const float* Wk    = (const float*)d_in[5];
    const float* Wv    = (const float*)d_in[6];
    const float* Wo    = (const float*)d_in[7];
    const float* W1    = (const float*)d_in[8];
    const float* b1    = (const float*)d_in[9];
    const float* W2    = (const float*)d_in[10];
    const float* b2    = (const float*)d_in[11];
    float* out = (float*)d_out;
    char* ws = (char*)d_ws;

    bf16*  wbuf = (bf16*)(ws + 0);           // 38 MB: transposed weights
    float* xnf  = (float*)(ws + 39845888);   // 16 MB: LN out fp32 -> x2 after Wo accum
    bf16*  hbuf = (bf16*)(ws + 56623104);    //  8 MB: rmsnorm bf16 -> x2 bf16
    bf16*  qkv  = (bf16*)(ws + 65011712);    // 36 MB: fused q|k|v; later FFN hidden
    bf16*  ob_  = (bf16*)(ws + 102760448);   // 12 MB: attention out
    bf16*  gb_  = qkv;

    // 1) LN rows + QKV weight transposes (independent; both feed the QKV GEMM)
    ln_qkvt_kernel<<<Sq + 3 * 1536, 256, 0, stream>>>(
        x, ln_g, ln_b, attng, xnf, hbuf, Wq, Wk, Wv, wbuf);

    // 2) fused QKV projection
    gemm_kernel<0><<<dim3(QKVDim / 128, Sq / 128, 1), 256, 0, stream>>>(
        hbuf, wbuf, Sq, QKVDim, Dm, Dm, qkv, nullptr, nullptr);

    // 3) attention (+ Wo transpose backfill; wbuf is dead during attention)
    attn_kernel<<<dim3(NH * Sq / 128 + 1536), 512, 0, stream>>>(qkv, ob_, Wo, wbuf);

    // 4) out-proj, split-K=2, atomic accumulate into xnf (holds residual)
    gemm_kernel<4><<<dim3(Dm / 128, Sq / 128, 2), 256, 0, stream>>>(
        ob_, wbuf, Sq, Dm, HDim, HDim / 2, nullptr, xnf, nullptr);
    cvt_prefill_kernel<<<(Sq * Dm) / (256 * 8), 256, 0, stream>>>(xnf, b2, hbuf, out, Dm);

    // 5) FFN1 (+bias+gelu)
    transpose_cvt_kernel<<<dim3(FF / 64, Dm / 64), 256, 0, stream>>>(W1, wbuf, Dm, FF);
    gemm_kernel<2><<<dim3(FF / 128, Sq / 128, 1), 256, 0, stream>>>(
        hbuf, wbuf, Sq, FF, Dm, Dm, gb_, nullptr, b1);

    // 6) FFN2, split-K=2, atomic accumulate into prefilled out
    transpose_cvt_kernel<<<dim3(Dm / 64, FF / 64), 256, 0, stream>>>(W2, wbuf, FF, Dm);
    gemm_kernel<4><<<dim3(Dm / 128, Sq / 128, 2), 256, 0, stream>>>(
        gb_, wbuf, Sq, Dm, FF, FF / 2, nullptr, out, nullptr);
}

// Round 17
// 445.992 us; speedup vs baseline: 1.0788x; 1.0788x over previous
//
#include <hip/hip_runtime.h>
#include <hip/hip_bf16.h>

#define Sq 2048
#define Dm 2048
#define HDim 3072
#define QKVDim 9216
#define NH 24
#define DH 128
#define FF 8192
#define ATT_SCALE 0.08838834764831845f

using bf16 = __hip_bfloat16;
typedef __attribute__((ext_vector_type(8))) short bf16x8;
typedef __attribute__((ext_vector_type(4))) float f32x4;
typedef unsigned int u32;
typedef unsigned long long u64;
typedef __attribute__((ext_vector_type(4))) u32 u32x4;

__device__ __forceinline__ void gload_lds16(const void* g, void* l) {
    __builtin_amdgcn_global_load_lds(
        (const __attribute__((address_space(1))) void*)g,
        (__attribute__((address_space(3))) void*)l, 16, 0, 0);
}

// ---------------- merged: LayerNorm+RMSNorm rows  |  QKV weight transpose ------
// blocks [0,Sq): LN row;  blocks [Sq, Sq+3*1536): 64x64 transpose tiles of Wq/Wk/Wv
__global__ __launch_bounds__(256) void ln_qkvt_kernel(
    const float* __restrict__ x, const float* __restrict__ g, const float* __restrict__ b,
    const float* __restrict__ ag, float* __restrict__ xnf, bf16* __restrict__ h,
    const float* __restrict__ Wq, const float* __restrict__ Wk, const float* __restrict__ Wv,
    bf16* __restrict__ Wt)
{
    union SmemU {
        float red[12];
        float tile[64][65];
    };
    __shared__ SmemU sm;
    int bid = blockIdx.x;
    int t = threadIdx.x;

    if (bid >= Sq) {
        int tb = bid - Sq;
        int z = tb / 1536, rr = tb % 1536;
        int bx = rr % 48, by = rr / 48;
        const float* W = z == 0 ? Wq : (z == 1 ? Wk : Wv);
        bf16* dst = Wt + (size_t)z * HDim * Dm;
        int n0 = bx * 64, k0 = by * 64;
        int lr = t >> 4, lc = (t & 15) * 4;
#pragma unroll
        for (int i = 0; i < 4; i++) {
            int r = lr + i * 16;
            f32x4 v = *reinterpret_cast<const f32x4*>(W + (size_t)(k0 + r) * HDim + n0 + lc);
            *reinterpret_cast<f32x4*>(&sm.tile[r][lc]) = v;
        }
        __syncthreads();
        int nr = t >> 3, kc = (t & 7) * 8;
#pragma unroll
        for (int i = 0; i < 2; i++) {
            int n = nr + i * 32;
            bf16 o8[8];
#pragma unroll
            for (int j = 0; j < 8; j++) o8[j] = __float2bfloat16(sm.tile[kc + j][n]);
            *reinterpret_cast<u32x4*>(dst + (size_t)(n0 + n) * Dm + k0 + kc) =
                *reinterpret_cast<const u32x4*>(o8);
        }
        return;
    }

    int row = bid;
    int lane = t & 63, wid = t >> 6;
    const float* xr = x + (size_t)row * Dm;

    float v[8];
    float sum = 0.f, ssq = 0.f;
#pragma unroll
    for (int i = 0; i < 8; i++) {
        float f = xr[t + 256 * i];
        v[i] = f; sum += f; ssq += f * f;
    }
#pragma unroll
    for (int off = 32; off > 0; off >>= 1) {
        sum += __shfl_down(sum, off);
        ssq += __shfl_down(ssq, off);
    }
    if (lane == 0) { sm.red[wid] = sum; sm.red[4 + wid] = ssq; }
    __syncthreads();
    sum = sm.red[0] + sm.red[1] + sm.red[2] + sm.red[3];
    ssq = sm.red[4] + sm.red[5] + sm.red[6] + sm.red[7];
    float mu = sum * (1.f / Dm);
    float var = ssq * (1.f / Dm) - mu * mu;
    float rstd = rsqrtf(var + 1e-5f);

    float xn[8];
    float s2 = 0.f;
#pragma unroll
    for (int i = 0; i < 8; i++) {
        int col = t + 256 * i;
        float xv = (v[i] - mu) * rstd * g[col] + b[col];
        xn[i] = xv;
        xnf[(size_t)row * Dm + col] = xv;
        s2 += xv * xv;
    }
#pragma unroll
    for (int off = 32; off > 0; off >>= 1) s2 += __shfl_down(s2, off);
    if (lane == 0) sm.red[8 + wid] = s2;
    __syncthreads();
    s2 = sm.red[8] + sm.red[9] + sm.red[10] + sm.red[11];
    float rms = rsqrtf(s2 * (1.f / Dm) + 1e-5f);
#pragma unroll
    for (int i = 0; i < 8; i++) {
        int col = t + 256 * i;
        h[(size_t)row * Dm + col] = __float2bfloat16(xn[i] * rms * ag[col]);
    }
}

// ---------------- transpose + fp32->bf16 convert: W[K][N] -> Wt[N][K] ----------------
// 64x64 tile, 256 threads
__global__ __launch_bounds__(256) void transpose_cvt_kernel(
    const float* __restrict__ W, bf16* __restrict__ Wt, int K, int N)
{
    __shared__ float tile[64][65];
    int n0 = blockIdx.x * 64, k0 = blockIdx.y * 64;
    int t = threadIdx.x;
    int lr = t >> 4, lc = (t & 15) * 4;
#pragma unroll
    for (int i = 0; i < 4; i++) {
        int r = lr + i * 16;
        f32x4 v = *reinterpret_cast<const f32x4*>(W + (size_t)(k0 + r) * N + n0 + lc);
        *reinterpret_cast<f32x4*>(&tile[r][lc]) = v;
    }
    __syncthreads();
    int nr = t >> 3, kc = (t & 7) * 8;
#pragma unroll
    for (int i = 0; i < 2; i++) {
        int n = nr + i * 32;
        bf16 o8[8];
#pragma unroll
        for (int j = 0; j < 8; j++) o8[j] = __float2bfloat16(tile[kc + j][n]);
        *reinterpret_cast<u32x4*>(Wt + (size_t)(n0 + n) * K + k0 + kc) =
            *reinterpret_cast<const u32x4*>(o8);
    }
}

// ---------------- fused: hb = bf16(xnf); out = xnf + b2 ----------------
__global__ __launch_bounds__(256) void cvt_prefill_kernel(
    const float* __restrict__ xnf, const float* __restrict__ bias,
    bf16* __restrict__ hb, float* __restrict__ o, int N)
{
    int i = (blockIdx.x * 256 + threadIdx.x) * 8;
    int col = i % N;
    f32x4 a = *reinterpret_cast<const f32x4*>(xnf + i);
    f32x4 b = *reinterpret_cast<const f32x4*>(xnf + i + 4);
    bf16 r[8];
#pragma unroll
    for (int j = 0; j < 4; j++) { r[j] = __float2bfloat16(a[j]); r[4 + j] = __float2bfloat16(b[j]); }
    *reinterpret_cast<u32x4*>(hb + i) = *reinterpret_cast<const u32x4*>(r);
    f32x4 b0 = *reinterpret_cast<const f32x4*>(bias + col);
    f32x4 b1v = *reinterpret_cast<const f32x4*>(bias + col + 4);
    f32x4 o0 = {a[0] + b0[0], a[1] + b0[1], a[2] + b0[2], a[3] + b0[3]};
    f32x4 o1 = {b[0] + b1v[0], b[1] + b1v[1], b[2] + b1v[2], b[3] + b1v[3]};
    *reinterpret_cast<f32x4*>(o + i) = o0;
    *reinterpret_cast<f32x4*>(o + i + 4) = o1;
}

// ---------------- 128x128 bf16 MFMA GEMM (m97 structure, BK=64, swizzled) ------
// EPI 0: Cb = bf16(acc);  EPI 2: Cb = bf16(gelu(acc+bias));  EPI 4: atomicAdd(Cf, acc)
template <int EPI>
__global__ __launch_bounds__(256, 4) void gemm_kernel(
    const bf16* __restrict__ A, const bf16* __restrict__ Bt,
    int M, int N, int K, int Ksplit,
    bf16* Cb, float* Cf, const float* __restrict__ bias)
{
    __shared__ __align__(16) bf16 As[128 * 64];
    __shared__ __align__(16) bf16 Bs[128 * 64];
    int m0 = blockIdx.y * 128, n0 = blockIdx.x * 128;
    int kbeg = blockIdx.z * Ksplit, kend = kbeg + Ksplit;
    int tid = threadIdx.x;
    int lane = tid & 63, w = tid >> 6;
    int wr = w >> 1, wc = w & 1;
    int l15 = lane & 15, lhi = lane >> 4;

    int srow = lane >> 3;
    int scol = ((lane & 7) ^ (lane >> 3)) * 8;

    const f32x4 zero4 = {0.f, 0.f, 0.f, 0.f};
    f32x4 acc[4][4];
#pragma unroll
    for (int m = 0; m < 4; m++)
#pragma unroll
        for (int n = 0; n < 4; n++) acc[m][n] = zero4;

    for (int k0 = kbeg; k0 < kend; k0 += 64) {
        __syncthreads();
#pragma unroll
        for (int c = 0; c < 4; c++) {
            int row = w * 32 + c * 8 + srow;
            gload_lds16(A + (size_t)(m0 + row) * K + k0 + scol,
                        (char*)As + w * 4096 + c * 1024);
            gload_lds16(Bt + (size_t)(n0 + row) * K + k0 + scol,
                        (char*)Bs + w * 4096 + c * 1024);
        }
        __syncthreads();
#pragma unroll
        for (int ks = 0; ks < 2; ks++) {
            bf16x8 af[4], bfr[4];
#pragma unroll
            for (int m = 0; m < 4; m++) {
                int r = wr * 64 + m * 16 + l15;
                af[m] = *reinterpret_cast<const bf16x8*>(
                    &As[r * 64 + (((ks << 2) + lhi) ^ (r & 7)) * 8]);
            }
#pragma unroll
            for (int n = 0; n < 4; n++) {
                int r = wc * 64 + n * 16 + l15;
                bfr[n] = *reinterpret_cast<const bf16x8*>(
                    &Bs[r * 64 + (((ks << 2) + lhi) ^ (r & 7)) * 8]);
            }
#pragma unroll
            for (int m = 0; m < 4; m++)
#pragma unroll
                for (int n = 0; n < 4; n++)
                    acc[m][n] = __builtin_amdgcn_mfma_f32_16x16x32_bf16(af[m], bfr[n], acc[m][n], 0, 0, 0);
        }
    }

#pragma unroll
    for (int m = 0; m < 4; m++) {
        int row = m0 + wr * 64 + m * 16 + lhi * 4;
#pragma unroll
        for (int n = 0; n < 4; n++) {
            int col = n0 + wc * 64 + n * 16 + l15;
#pragma unroll
            for (int j = 0; j < 4; j++) {
                float vv = acc[m][n][j];
                size_t idx = (size_t)(row + j) * N + col;
                if (EPI == 0) {
                    Cb[idx] = __float2bfloat16(vv);
                } else if (EPI == 2) {
                    float o = vv + bias[col];
                    float u = 1.5957691216057308f * (o + 0.044715f * o * o * o);
                    Cb[idx] = __float2bfloat16(o / (1.0f + __expf(-u)));
                } else {
                    atomicAdd(&Cf[idx], vv);
                }
            }
        }
    }
}

// ---------------- flash-style causal attention, 8-wave QBLK=128 (r15 version) --
__global__ __launch_bounds__(512) void attn_kernel(
    const bf16* __restrict__ qkv, bf16* __restrict__ o)
{
    __shared__ __align__(16) bf16 KsF[2][64 * 128];   // swizzled: slot s of row r = block s^(r&7)
    __shared__ __align__(16) bf16 VtF[128 * 72];      // V^T, kv-block XOR swizzle (single buffer)
    __shared__ __align__(16) bf16 Pl[8][16][76];      // per-wave P tile, padded stride
    int rank = blockIdx.x;
    int qb = (Sq / 128 - 1) - rank / NH;   // heaviest first
    int head = rank % NH;
    const bf16* q = qkv + head * DH;
    const bf16* k = qkv + HDim + head * DH;
    const bf16* v = qkv + 2 * HDim + head * DH;
    int tid = threadIdx.x, lane = tid & 63, w = tid >> 6;   // w 0..7
    int l15 = lane & 15, lhi = lane >> 4;
    int qrow0 = qb * 128 + w * 16;

    bf16x8 aq[4];
    const bf16* qbase = q + (size_t)(qrow0 + l15) * QKVDim;
#pragma unroll
    for (int kk = 0; kk < 4; kk++)
        aq[kk] = *reinterpret_cast<const bf16x8*>(qbase + kk * 32 + lhi * 8);

    bf16x8 vones;
#pragma unroll
    for (int j = 0; j < 8; j++) vones[j] = (short)0x3F80;

    int vkv = lhi * 2 + (w & 1) + (w >> 1) * 8;   // 0..31; +i*32
    int vd0 = l15 * 8;
    int vxr = l15 & 7;
    const bf16* vbase = v + (size_t)vkv * QKVDim + vd0;

    const f32x4 zero4 = {0.f, 0.f, 0.f, 0.f};
    f32x4 acc_o[8];
#pragma unroll
    for (int db = 0; db < 8; db++) acc_o[db] = zero4;
    f32x4 acc_l = zero4;
    float mrow[4];
#pragma unroll
    for (int r = 0; r < 4; r++) mrow[r] = -1e30f;

    int nt = 2 * qb + 2;

    // prologue: K(0) -> KsF[0] via DMA; V(0) -> VtF directly
    {
#pragma unroll
        for (int c = 0; c < 2; c++) {
            int row = w * 8 + c * 4 + lhi;
            int cb = l15 ^ (row & 7);
            gload_lds16(k + (size_t)row * QKVDim + cb * 8,
                        (char*)&KsF[0][0] + w * 2048 + c * 1024);
        }
#pragma unroll
        for (int i = 0; i < 2; i++) {
            int kv = vkv + i * 32;
            bf16x8 vv = *reinterpret_cast<const bf16x8*>(vbase + (size_t)(i * 32) * QKVDim);
            int vb = kv >> 3, kr = kv & 7;
#pragma unroll
            for (int j = 0; j < 8; j++)
                VtF[(vd0 + j) * 72 + ((vb ^ vxr) << 3) + kr] = ((const bf16*)&vv)[j];
        }
        __syncthreads();
    }

    for (int kb = 0; kb < nt; kb++) {
        int kv0 = kb * 64;
        int p = kb & 1;
        bf16x8 vreg[2];
        bool pref = (kb + 1 < nt);
        if (pref) {
            int nv0 = kv0 + 64;
#pragma unroll
            for (int c = 0; c < 2; c++) {
                int row = w * 8 + c * 4 + lhi;
                int cb = l15 ^ (row & 7);
                gload_lds16(k + (size_t)(nv0 + row) * QKVDim + cb * 8,
                            (char*)&KsF[p ^ 1][0] + w * 2048 + c * 1024);
            }
#pragma unroll
            for (int i = 0; i < 2; i++)
                vreg[i] = *reinterpret_cast<const bf16x8*>(
                    vbase + (size_t)(nv0 + i * 32) * QKVDim);
        }

        bool active = (kv0 <= qrow0 + 15);   // wave-uniform causal skip
        if (active) {
            f32x4 sacc[4];
            __builtin_amdgcn_s_setprio(1);
#pragma unroll
            for (int nb = 0; nb < 4; nb++) {
                sacc[nb] = zero4;
                int krow = nb * 16 + l15;
#pragma unroll
                for (int kk = 0; kk < 4; kk++) {
                    const char* kp = (const char*)&KsF[p][0] + krow * 256 +
                                     ((kk * 64 + lhi * 16) ^ ((krow & 7) << 4));
                    bf16x8 bk = *reinterpret_cast<const bf16x8*>(kp);
                    sacc[nb] = __builtin_amdgcn_mfma_f32_16x16x32_bf16(aq[kk], bk, sacc[nb], 0, 0, 0);
                }
            }
            __builtin_amdgcn_s_setprio(0);

            bool msk = (kv0 + 63 > qrow0);
            float sv[4][4];
            float pm[4];
#pragma unroll
            for (int r = 0; r < 4; r++) pm[r] = -1e30f;
#pragma unroll
            for (int nb = 0; nb < 4; nb++) {
                int kvc = kv0 + nb * 16 + l15;
#pragma unroll
                for (int r = 0; r < 4; r++) {
                    int qr = qrow0 + lhi * 4 + r;
                    float s = sacc[nb][r] * ATT_SCALE;
                    if (msk && kvc > qr) s = -1e30f;
                    sv[nb][r] = s;
                    pm[r] = fmaxf(pm[r], s);
                }
            }
#pragma unroll
            for (int off = 1; off < 16; off <<= 1)
#pragma unroll
                for (int r = 0; r < 4; r++)
                    pm[r] = fmaxf(pm[r], __shfl_xor(pm[r], off));

            float nm[4];
            bool need = false;
#pragma unroll
            for (int r = 0; r < 4; r++) {
                nm[r] = fmaxf(mrow[r], pm[r]);
                need = need || (pm[r] > mrow[r] + 8.f);
            }
            if (__any(need)) {
#pragma unroll
                for (int r = 0; r < 4; r++) {
                    float sc = __expf(mrow[r] - nm[r]);
                    mrow[r] = nm[r];
                    acc_l[r] *= sc;
#pragma unroll
                    for (int db = 0; db < 8; db++) acc_o[db][r] *= sc;
                }
            }

#pragma unroll
            for (int nb = 0; nb < 4; nb++)
#pragma unroll
                for (int r = 0; r < 4; r++)
                    sv[nb][r] = __expf(sv[nb][r] - mrow[r]);

#pragma unroll
            for (int nb = 0; nb < 4; nb++)
#pragma unroll
                for (int r = 0; r < 4; r++)
                    Pl[w][lhi * 4 + r][nb * 16 + l15] = __float2bfloat16(sv[nb][r]);

            __builtin_amdgcn_s_setprio(1);
#pragma unroll
            for (int ks = 0; ks < 2; ks++) {
                bf16x8 ap = *reinterpret_cast<const bf16x8*>(&Pl[w][l15][ks * 32 + lhi * 8]);
                acc_l = __builtin_amdgcn_mfma_f32_16x16x32_bf16(ap, vones, acc_l, 0, 0, 0);
#pragma unroll
                for (int db = 0; db < 8; db++) {
                    int dv = db * 16 + l15;
                    int blk = (ks * 4 + lhi) ^ ((dv >> 3) & 7);
                    bf16x8 bv = *reinterpret_cast<const bf16x8*>(&VtF[dv * 72 + blk * 8]);
                    acc_o[db] = __builtin_amdgcn_mfma_f32_16x16x32_bf16(ap, bv, acc_o[db], 0, 0, 0);
                }
            }
            __builtin_amdgcn_s_setprio(0);
        }

        __syncthreads();   // barrier1: all waves done reading VtF
        if (pref) {
#pragma unroll
            for (int i = 0; i < 2; i++) {
                int kv = vkv + i * 32;
                int vb = kv >> 3, kr = kv & 7;
#pragma unroll
                for (int j = 0; j < 8; j++)
                    VtF[(vd0 + j) * 72 + ((vb ^ vxr) << 3) + kr] = ((const bf16*)&vreg[i])[j];
            }
        }
        __syncthreads();   // barrier2: V(kb+1) published; K(kb+1) DMA drained
    }

#pragma unroll
    for (int db = 0; db < 8; db++)
#pragma unroll
        for (int r = 0; r < 4; r++) {
            int qr = qrow0 + lhi * 4 + r;
            float val = acc_o[db][r] / acc_l[r];
            o[(size_t)qr * HDim + head * DH + db * 16 + l15] = __float2bfloat16(val);
        }
}

// ---------------- host launch ----------------
extern "C" void kernel_launch(void* const* d_in, const int* in_sizes, int n_in,
                              void* d_out, int out_size, void* d_ws, size_t ws_size,
                              hipStream_t stream)
{
    const float* x     = (const float*)d_in[0];
    const float* ln_g  = (const float*)d_in[1];
    const float* ln_b  = (const float*)d_in[2];
    const float* attng = (const float*)d_in[3];
    const float* Wq    = (const float*)d_in[4];
    const float* Wk    = (const float*)d_in[5];
    const float* Wv    = (const float*)d_in[6];
    const float* Wo    = (const float*)d_in[7];
    const float* W1    = (const float*)d_in[8];
    const float* b1    = (const float*)d_in[9];
    const float* W2    = (const float*)d_in[10];
    const float* b2    = (const float*)d_in[11];
    float* out = (float*)d_out;
    char* ws = (char*)d_ws;

    bf16*  wbuf = (bf16*)(ws + 0);           // 38 MB: transposed weights
    float* xnf  = (float*)(ws + 39845888);   // 16 MB: LN out fp32 -> x2 after Wo accum
    bf16*  hbuf = (bf16*)(ws + 56623104);    //  8 MB: rmsnorm bf16 -> x2 bf16
    bf16*  qkv  = (bf16*)(ws + 65011712);    // 36 MB: fused q|k|v; later FFN hidden
    bf16*  ob_  = (bf16*)(ws + 102760448);   // 12 MB: attention out
    bf16*  gb_  = qkv;

    // 1) LN rows + QKV weight transposes (merged; both feed the QKV GEMM)
    ln_qkvt_kernel<<<Sq + 3 * 1536, 256, 0, stream>>>(
        x, ln_g, ln_b, attng, xnf, hbuf, Wq, Wk, Wv, wbuf);

    // 2) fused QKV projection
    gemm_kernel<0><<<dim3(QKVDim / 128, Sq / 128, 1), 256, 0, stream>>>(
        hbuf, wbuf, Sq, QKVDim, Dm, Dm, qkv, nullptr, nullptr);

    // 3) attention (standalone r15 kernel)
    attn_kernel<<<dim3(NH * Sq / 128), 512, 0, stream>>>(qkv, ob_);

    // 4) out-proj, split-K=2, atomic accumulate into xnf (holds residual)
    transpose_cvt_kernel<<<dim3(Dm / 64, HDim / 64), 256, 0, stream>>>(Wo, wbuf, HDim, Dm);
    gemm_kernel<4><<<dim3(Dm / 128, Sq / 128, 2), 256, 0, stream>>>(
        ob_, wbuf, Sq, Dm, HDim, HDim / 2, nullptr, xnf, nullptr);
    cvt_prefill_kernel<<<(Sq * Dm) / (256 * 8), 256, 0, stream>>>(xnf, b2, hbuf, out, Dm);

    // 5) FFN1 (+bias+gelu)
    transpose_cvt_kernel<<<dim3(FF / 64, Dm / 64), 256, 0, stream>>>(W1, wbuf, Dm, FF);
    gemm_kernel<2><<<dim3(FF / 128, Sq / 128, 1), 256, 0, stream>>>(
        hbuf, wbuf, Sq, FF, Dm, Dm, gb_, nullptr, b1);

    // 6) FFN2, split-K=2, atomic accumulate into prefilled out
    transpose_cvt_kernel<<<dim3(Dm / 64, FF / 64), 256, 0, stream>>>(W2, wbuf, FF, Dm);
    gemm_kernel<4><<<dim3(Dm / 128, Sq / 128, 2), 256, 0, stream>>>(
        gb_, wbuf, Sq, Dm, FF, FF / 2, nullptr, out, nullptr);
}

// Round 18
// 443.733 us; speedup vs baseline: 1.0842x; 1.0051x over previous
//
#include <hip/hip_runtime.h>
#include <hip/hip_bf16.h>

#define Sq 2048
#define Dm 2048
#define HDim 3072
#define QKVDim 9216
#define NH 24
#define DH 128
#define FF 8192
#define ATT_SCALE 0.08838834764831845f

using bf16 = __hip_bfloat16;
typedef __attribute__((ext_vector_type(8))) short bf16x8;
typedef __attribute__((ext_vector_type(4))) float f32x4;
typedef unsigned int u32;
typedef unsigned long long u64;
typedef __attribute__((ext_vector_type(4))) u32 u32x4;

__device__ __forceinline__ void gload_lds16(const void* g, void* l) {
    __builtin_amdgcn_global_load_lds(
        (const __attribute__((address_space(1))) void*)g,
        (__attribute__((address_space(3))) void*)l, 16, 0, 0);
}

// ---------------- merged: LayerNorm+RMSNorm rows  |  QKV weight transpose ------
// blocks [0,Sq): LN row;  blocks [Sq, Sq+3*1536): 64x64 transpose tiles of Wq/Wk/Wv
__global__ __launch_bounds__(256) void ln_qkvt_kernel(
    const float* __restrict__ x, const float* __restrict__ g, const float* __restrict__ b,
    const float* __restrict__ ag, float* __restrict__ xnf, bf16* __restrict__ h,
    const float* __restrict__ Wq, const float* __restrict__ Wk, const float* __restrict__ Wv,
    bf16* __restrict__ Wt)
{
    union SmemU {
        float red[12];
        float tile[64][65];
    };
    __shared__ SmemU sm;
    int bid = blockIdx.x;
    int t = threadIdx.x;

    if (bid >= Sq) {
        int tb = bid - Sq;
        int z = tb / 1536, rr = tb % 1536;
        int bx = rr % 48, by = rr / 48;
        const float* W = z == 0 ? Wq : (z == 1 ? Wk : Wv);
        bf16* dst = Wt + (size_t)z * HDim * Dm;
        int n0 = bx * 64, k0 = by * 64;
        int lr = t >> 4, lc = (t & 15) * 4;
#pragma unroll
        for (int i = 0; i < 4; i++) {
            int r = lr + i * 16;
            f32x4 v = *reinterpret_cast<const f32x4*>(W + (size_t)(k0 + r) * HDim + n0 + lc);
            *reinterpret_cast<f32x4*>(&sm.tile[r][lc]) = v;
        }
        __syncthreads();
        int nr = t >> 3, kc = (t & 7) * 8;
#pragma unroll
        for (int i = 0; i < 2; i++) {
            int n = nr + i * 32;
            bf16 o8[8];
#pragma unroll
            for (int j = 0; j < 8; j++) o8[j] = __float2bfloat16(sm.tile[kc + j][n]);
            *reinterpret_cast<u32x4*>(dst + (size_t)(n0 + n) * Dm + k0 + kc) =
                *reinterpret_cast<const u32x4*>(o8);
        }
        return;
    }

    int row = bid;
    int lane = t & 63, wid = t >> 6;
    const float* xr = x + (size_t)row * Dm;

    float v[8];
    float sum = 0.f, ssq = 0.f;
#pragma unroll
    for (int i = 0; i < 8; i++) {
        float f = xr[t + 256 * i];
        v[i] = f; sum += f; ssq += f * f;
    }
#pragma unroll
    for (int off = 32; off > 0; off >>= 1) {
        sum += __shfl_down(sum, off);
        ssq += __shfl_down(ssq, off);
    }
    if (lane == 0) { sm.red[wid] = sum; sm.red[4 + wid] = ssq; }
    __syncthreads();
    sum = sm.red[0] + sm.red[1] + sm.red[2] + sm.red[3];
    ssq = sm.red[4] + sm.red[5] + sm.red[6] + sm.red[7];
    float mu = sum * (1.f / Dm);
    float var = ssq * (1.f / Dm) - mu * mu;
    float rstd = rsqrtf(var + 1e-5f);

    float xn[8];
    float s2 = 0.f;
#pragma unroll
    for (int i = 0; i < 8; i++) {
        int col = t + 256 * i;
        float xv = (v[i] - mu) * rstd * g[col] + b[col];
        xn[i] = xv;
        xnf[(size_t)row * Dm + col] = xv;
        s2 += xv * xv;
    }
#pragma unroll
    for (int off = 32; off > 0; off >>= 1) s2 += __shfl_down(s2, off);
    if (lane == 0) sm.red[8 + wid] = s2;
    __syncthreads();
    s2 = sm.red[8] + sm.red[9] + sm.red[10] + sm.red[11];
    float rms = rsqrtf(s2 * (1.f / Dm) + 1e-5f);
#pragma unroll
    for (int i = 0; i < 8; i++) {
        int col = t + 256 * i;
        h[(size_t)row * Dm + col] = __float2bfloat16(xn[i] * rms * ag[col]);
    }
}

// ---------------- transpose + fp32->bf16 convert: W[K][N] -> Wt[N][K] ----------------
// 64x64 tile, 256 threads
__global__ __launch_bounds__(256) void transpose_cvt_kernel(
    const float* __restrict__ W, bf16* __restrict__ Wt, int K, int N)
{
    __shared__ float tile[64][65];
    int n0 = blockIdx.x * 64, k0 = blockIdx.y * 64;
    int t = threadIdx.x;
    int lr = t >> 4, lc = (t & 15) * 4;
#pragma unroll
    for (int i = 0; i < 4; i++) {
        int r = lr + i * 16;
        f32x4 v = *reinterpret_cast<const f32x4*>(W + (size_t)(k0 + r) * N + n0 + lc);
        *reinterpret_cast<f32x4*>(&tile[r][lc]) = v;
    }
    __syncthreads();
    int nr = t >> 3, kc = (t & 7) * 8;
#pragma unroll
    for (int i = 0; i < 2; i++) {
        int n = nr + i * 32;
        bf16 o8[8];
#pragma unroll
        for (int j = 0; j < 8; j++) o8[j] = __float2bfloat16(tile[kc + j][n]);
        *reinterpret_cast<u32x4*>(Wt + (size_t)(n0 + n) * K + k0 + kc) =
            *reinterpret_cast<const u32x4*>(o8);
    }
}

// ---------------- merged: cvt_prefill | W1 transpose ----------------
// blocks [0, 2048): hb = bf16(xnf), out = xnf + b2
// blocks [2048, 2048+4096): 64x64 transpose tiles of W1[Dm][FF] -> Wt[FF][Dm]
__global__ __launch_bounds__(256) void cvtpf_w1t_kernel(
    const float* __restrict__ xnf, const float* __restrict__ bias,
    bf16* __restrict__ hb, float* __restrict__ o,
    const float* __restrict__ W1, bf16* __restrict__ Wt)
{
    __shared__ float tile[64][65];
    int bid = blockIdx.x;
    int t = threadIdx.x;

    if (bid >= 2048) {
        int tb = bid - 2048;
        int bx = tb % (FF / 64), by = tb / (FF / 64);   // bx over FF, by over Dm
        int n0 = bx * 64, k0 = by * 64;
        int lr = t >> 4, lc = (t & 15) * 4;
#pragma unroll
        for (int i = 0; i < 4; i++) {
            int r = lr + i * 16;
            f32x4 v = *reinterpret_cast<const f32x4*>(W1 + (size_t)(k0 + r) * FF + n0 + lc);
            *reinterpret_cast<f32x4*>(&tile[r][lc]) = v;
        }
        __syncthreads();
        int nr = t >> 3, kc = (t & 7) * 8;
#pragma unroll
        for (int i = 0; i < 2; i++) {
            int n = nr + i * 32;
            bf16 o8[8];
#pragma unroll
            for (int j = 0; j < 8; j++) o8[j] = __float2bfloat16(tile[kc + j][n]);
            *reinterpret_cast<u32x4*>(Wt + (size_t)(n0 + n) * Dm + k0 + kc) =
                *reinterpret_cast<const u32x4*>(o8);
        }
        return;
    }

    int i = (bid * 256 + t) * 8;
    int col = i % Dm;
    f32x4 a = *reinterpret_cast<const f32x4*>(xnf + i);
    f32x4 b = *reinterpret_cast<const f32x4*>(xnf + i + 4);
    bf16 r[8];
#pragma unroll
    for (int j = 0; j < 4; j++) { r[j] = __float2bfloat16(a[j]); r[4 + j] = __float2bfloat16(b[j]); }
    *reinterpret_cast<u32x4*>(hb + i) = *reinterpret_cast<const u32x4*>(r);
    f32x4 b0 = *reinterpret_cast<const f32x4*>(bias + col);
    f32x4 b1v = *reinterpret_cast<const f32x4*>(bias + col + 4);
    f32x4 o0 = {a[0] + b0[0], a[1] + b0[1], a[2] + b0[2], a[3] + b0[3]};
    f32x4 o1 = {b[0] + b1v[0], b[1] + b1v[1], b[2] + b1v[2], b[3] + b1v[3]};
    *reinterpret_cast<f32x4*>(o + i) = o0;
    *reinterpret_cast<f32x4*>(o + i + 4) = o1;
}

// ---------------- 128x128 bf16 MFMA GEMM (m97 structure, BK=64, swizzled) ------
// EPI 0: Cb = bf16(acc);  EPI 2: Cb = bf16(gelu(acc+bias));  EPI 4: atomicAdd(Cf, acc)
template <int EPI>
__global__ __launch_bounds__(256, 4) void gemm_kernel(
    const bf16* __restrict__ A, const bf16* __restrict__ Bt,
    int M, int N, int K, int Ksplit,
    bf16* Cb, float* Cf, const float* __restrict__ bias)
{
    __shared__ __align__(16) bf16 As[128 * 64];
    __shared__ __align__(16) bf16 Bs[128 * 64];
    int m0 = blockIdx.y * 128, n0 = blockIdx.x * 128;
    int kbeg = blockIdx.z * Ksplit, kend = kbeg + Ksplit;
    int tid = threadIdx.x;
    int lane = tid & 63, w = tid >> 6;
    int wr = w >> 1, wc = w & 1;
    int l15 = lane & 15, lhi = lane >> 4;

    int srow = lane >> 3;
    int scol = ((lane & 7) ^ (lane >> 3)) * 8;

    const f32x4 zero4 = {0.f, 0.f, 0.f, 0.f};
    f32x4 acc[4][4];
#pragma unroll
    for (int m = 0; m < 4; m++)
#pragma unroll
        for (int n = 0; n < 4; n++) acc[m][n] = zero4;

    for (int k0 = kbeg; k0 < kend; k0 += 64) {
        __syncthreads();
#pragma unroll
        for (int c = 0; c < 4; c++) {
            int row = w * 32 + c * 8 + srow;
            gload_lds16(A + (size_t)(m0 + row) * K + k0 + scol,
                        (char*)As + w * 4096 + c * 1024);
            gload_lds16(Bt + (size_t)(n0 + row) * K + k0 + scol,
                        (char*)Bs + w * 4096 + c * 1024);
        }
        __syncthreads();
#pragma unroll
        for (int ks = 0; ks < 2; ks++) {
            bf16x8 af[4], bfr[4];
#pragma unroll
            for (int m = 0; m < 4; m++) {
                int r = wr * 64 + m * 16 + l15;
                af[m] = *reinterpret_cast<const bf16x8*>(
                    &As[r * 64 + (((ks << 2) + lhi) ^ (r & 7)) * 8]);
            }
#pragma unroll
            for (int n = 0; n < 4; n++) {
                int r = wc * 64 + n * 16 + l15;
                bfr[n] = *reinterpret_cast<const bf16x8*>(
                    &Bs[r * 64 + (((ks << 2) + lhi) ^ (r & 7)) * 8]);
            }
#pragma unroll
            for (int m = 0; m < 4; m++)
#pragma unroll
                for (int n = 0; n < 4; n++)
                    acc[m][n] = __builtin_amdgcn_mfma_f32_16x16x32_bf16(af[m], bfr[n], acc[m][n], 0, 0, 0);
        }
    }

#pragma unroll
    for (int m = 0; m < 4; m++) {
        int row = m0 + wr * 64 + m * 16 + lhi * 4;
#pragma unroll
        for (int n = 0; n < 4; n++) {
            int col = n0 + wc * 64 + n * 16 + l15;
#pragma unroll
            for (int j = 0; j < 4; j++) {
                float vv = acc[m][n][j];
                size_t idx = (size_t)(row + j) * N + col;
                if (EPI == 0) {
                    Cb[idx] = __float2bfloat16(vv);
                } else if (EPI == 2) {
                    float o = vv + bias[col];
                    float u = 1.5957691216057308f * (o + 0.044715f * o * o * o);
                    Cb[idx] = __float2bfloat16(o / (1.0f + __expf(-u)));
                } else {
                    atomicAdd(&Cf[idx], vv);
                }
            }
        }
    }
}

// ---------------- flash-style causal attention, 8-wave QBLK=128 (r15 version) --
__global__ __launch_bounds__(512) void attn_kernel(
    const bf16* __restrict__ qkv, bf16* __restrict__ o)
{
    __shared__ __align__(16) bf16 KsF[2][64 * 128];   // swizzled: slot s of row r = block s^(r&7)
    __shared__ __align__(16) bf16 VtF[128 * 72];      // V^T, kv-block XOR swizzle (single buffer)
    __shared__ __align__(16) bf16 Pl[8][16][76];      // per-wave P tile, padded stride
    int rank = blockIdx.x;
    int qb = (Sq / 128 - 1) - rank / NH;   // heaviest first
    int head = rank % NH;
    const bf16* q = qkv + head * DH;
    const bf16* k = qkv + HDim + head * DH;
    const bf16* v = qkv + 2 * HDim + head * DH;
    int tid = threadIdx.x, lane = tid & 63, w = tid >> 6;   // w 0..7
    int l15 = lane & 15, lhi = lane >> 4;
    int qrow0 = qb * 128 + w * 16;

    bf16x8 aq[4];
    const bf16* qbase = q + (size_t)(qrow0 + l15) * QKVDim;
#pragma unroll
    for (int kk = 0; kk < 4; kk++)
        aq[kk] = *reinterpret_cast<const bf16x8*>(qbase + kk * 32 + lhi * 8);

    bf16x8 vones;
#pragma unroll
    for (int j = 0; j < 8; j++) vones[j] = (short)0x3F80;

    int vkv = lhi * 2 + (w & 1) + (w >> 1) * 8;   // 0..31; +i*32
    int vd0 = l15 * 8;
    int vxr = l15 & 7;
    const bf16* vbase = v + (size_t)vkv * QKVDim + vd0;

    const f32x4 zero4 = {0.f, 0.f, 0.f, 0.f};
    f32x4 acc_o[8];
#pragma unroll
    for (int db = 0; db < 8; db++) acc_o[db] = zero4;
    f32x4 acc_l = zero4;
    float mrow[4];
#pragma unroll
    for (int r = 0; r < 4; r++) mrow[r] = -1e30f;

    int nt = 2 * qb + 2;

    // prologue: K(0) -> KsF[0] via DMA; V(0) -> VtF directly
    {
#pragma unroll
        for (int c = 0; c < 2; c++) {
            int row = w * 8 + c * 4 + lhi;
            int cb = l15 ^ (row & 7);
            gload_lds16(k + (size_t)row * QKVDim + cb * 8,
                        (char*)&KsF[0][0] + w * 2048 + c * 1024);
        }
#pragma unroll
        for (int i = 0; i < 2; i++) {
            int kv = vkv + i * 32;
            bf16x8 vv = *reinterpret_cast<const bf16x8*>(vbase + (size_t)(i * 32) * QKVDim);
            int vb = kv >> 3, kr = kv & 7;
#pragma unroll
            for (int j = 0; j < 8; j++)
                VtF[(vd0 + j) * 72 + ((vb ^ vxr) << 3) + kr] = ((const bf16*)&vv)[j];
        }
        __syncthreads();
    }

    for (int kb = 0; kb < nt; kb++) {
        int kv0 = kb * 64;
        int p = kb & 1;
        bf16x8 vreg[2];
        bool pref = (kb + 1 < nt);
        if (pref) {
            int nv0 = kv0 + 64;
#pragma unroll
            for (int c = 0; c < 2; c++) {
                int row = w * 8 + c * 4 + lhi;
                int cb = l15 ^ (row & 7);
                gload_lds16(k + (size_t)(nv0 + row) * QKVDim + cb * 8,
                            (char*)&KsF[p ^ 1][0] + w * 2048 + c * 1024);
            }
#pragma unroll
            for (int i = 0; i < 2; i++)
                vreg[i] = *reinterpret_cast<const bf16x8*>(
                    vbase + (size_t)(nv0 + i * 32) * QKVDim);
        }

        bool active = (kv0 <= qrow0 + 15);   // wave-uniform causal skip
        if (active) {
            f32x4 sacc[4];
            __builtin_amdgcn_s_setprio(1);
#pragma unroll
            for (int nb = 0; nb < 4; nb++) {
                sacc[nb] = zero4;
                int krow = nb * 16 + l15;
#pragma unroll
                for (int kk = 0; kk < 4; kk++) {
                    const char* kp = (const char*)&KsF[p][0] + krow * 256 +
                                     ((kk * 64 + lhi * 16) ^ ((krow & 7) << 4));
                    bf16x8 bk = *reinterpret_cast<const bf16x8*>(kp);
                    sacc[nb] = __builtin_amdgcn_mfma_f32_16x16x32_bf16(aq[kk], bk, sacc[nb], 0, 0, 0);
                }
            }
            __builtin_amdgcn_s_setprio(0);

            bool msk = (kv0 + 63 > qrow0);
            float sv[4][4];
            float pm[4];
#pragma unroll
            for (int r = 0; r < 4; r++) pm[r] = -1e30f;
#pragma unroll
            for (int nb = 0; nb < 4; nb++) {
                int kvc = kv0 + nb * 16 + l15;
#pragma unroll
                for (int r = 0; r < 4; r++) {
                    int qr = qrow0 + lhi * 4 + r;
                    float s = sacc[nb][r] * ATT_SCALE;
                    if (msk && kvc > qr) s = -1e30f;
                    sv[nb][r] = s;
                    pm[r] = fmaxf(pm[r], s);
                }
            }
#pragma unroll
            for (int off = 1; off < 16; off <<= 1)
#pragma unroll
                for (int r = 0; r < 4; r++)
                    pm[r] = fmaxf(pm[r], __shfl_xor(pm[r], off));

            float nm[4];
            bool need = false;
#pragma unroll
            for (int r = 0; r < 4; r++) {
                nm[r] = fmaxf(mrow[r], pm[r]);
                need = need || (pm[r] > mrow[r] + 8.f);
            }
            if (__any(need)) {
#pragma unroll
                for (int r = 0; r < 4; r++) {
                    float sc = __expf(mrow[r] - nm[r]);
                    mrow[r] = nm[r];
                    acc_l[r] *= sc;
#pragma unroll
                    for (int db = 0; db < 8; db++) acc_o[db][r] *= sc;
                }
            }

#pragma unroll
            for (int nb = 0; nb < 4; nb++)
#pragma unroll
                for (int r = 0; r < 4; r++)
                    sv[nb][r] = __expf(sv[nb][r] - mrow[r]);

#pragma unroll
            for (int nb = 0; nb < 4; nb++)
#pragma unroll
                for (int r = 0; r < 4; r++)
                    Pl[w][lhi * 4 + r][nb * 16 + l15] = __float2bfloat16(sv[nb][r]);

            __builtin_amdgcn_s_setprio(1);
#pragma unroll
            for (int ks = 0; ks < 2; ks++) {
                bf16x8 ap = *reinterpret_cast<const bf16x8*>(&Pl[w][l15][ks * 32 + lhi * 8]);
                acc_l = __builtin_amdgcn_mfma_f32_16x16x32_bf16(ap, vones, acc_l, 0, 0, 0);
#pragma unroll
                for (int db = 0; db < 8; db++) {
                    int dv = db * 16 + l15;
                    int blk = (ks * 4 + lhi) ^ ((dv >> 3) & 7);
                    bf16x8 bv = *reinterpret_cast<const bf16x8*>(&VtF[dv * 72 + blk * 8]);
                    acc_o[db] = __builtin_amdgcn_mfma_f32_16x16x32_bf16(ap, bv, acc_o[db], 0, 0, 0);
                }
            }
            __builtin_amdgcn_s_setprio(0);
        }

        __syncthreads();   // barrier1: all waves done reading VtF
        if (pref) {
#pragma unroll
            for (int i = 0; i < 2; i++) {
                int kv = vkv + i * 32;
                int vb = kv >> 3, kr = kv & 7;
#pragma unroll
                for (int j = 0; j < 8; j++)
                    VtF[(vd0 + j) * 72 + ((vb ^ vxr) << 3) + kr] = ((const bf16*)&vreg[i])[j];
            }
        }
        __syncthreads();   // barrier2: V(kb+1) published; K(kb+1) DMA drained
    }

#pragma unroll
    for (int db = 0; db < 8; db++)
#pragma unroll
        for (int r = 0; r < 4; r++) {
            int qr = qrow0 + lhi * 4 + r;
            float val = acc_o[db][r] / acc_l[r];
            o[(size_t)qr * HDim + head * DH + db * 16 + l15] = __float2bfloat16(val);
        }
}

// ---------------- host launch ----------------
extern "C" void kernel_launch(void* const* d_in, const int* in_sizes, int n_in,
                              void* d_out, int out_size, void* d_ws, size_t ws_size,
                              hipStream_t stream)
{
    const float* x     = (const float*)d_in[0];
    const float* ln_g  = (const float*)d_in[1];
    const float* ln_b  = (const float*)d_in[2];
    const float* attng = (const float*)d_in[3];
    const float* Wq    = (const float*)d_in[4];
    const float* Wk    = (const float*)d_in[5];
    const float* Wv    = (const float*)d_in[6];
    const float* Wo    = (const float*)d_in[7];
    const float* W1    = (const float*)d_in[8];
    const float* b1    = (const float*)d_in[9];
    const float* W2    = (const float*)d_in[10];
    const float* b2    = (const float*)d_in[11];
    float* out = (float*)d_out;
    char* ws = (char*)d_ws;

    bf16*  wbuf = (bf16*)(ws + 0);           // 38 MB: transposed weights
    float* xnf  = (float*)(ws + 39845888);   // 16 MB: LN out fp32 -> x2 after Wo accum
    bf16*  hbuf = (bf16*)(ws + 56623104);    //  8 MB: rmsnorm bf16 -> x2 bf16
    bf16*  qkv  = (bf16*)(ws + 65011712);    // 36 MB: fused q|k|v; later FFN hidden
    bf16*  ob_  = (bf16*)(ws + 102760448);   // 12 MB: attention out
    bf16*  gb_  = qkv;

    // 1) LN rows + QKV weight transposes (merged)
    ln_qkvt_kernel<<<Sq + 3 * 1536, 256, 0, stream>>>(
        x, ln_g, ln_b, attng, xnf, hbuf, Wq, Wk, Wv, wbuf);

    // 2) fused QKV projection
    gemm_kernel<0><<<dim3(QKVDim / 128, Sq / 128, 1), 256, 0, stream>>>(
        hbuf, wbuf, Sq, QKVDim, Dm, Dm, qkv, nullptr, nullptr);

    // 3) attention
    attn_kernel<<<dim3(NH * Sq / 128), 512, 0, stream>>>(qkv, ob_);

    // 4) out-proj, split-K=2, atomic accumulate into xnf (holds residual)
    transpose_cvt_kernel<<<dim3(Dm / 64, HDim / 64), 256, 0, stream>>>(Wo, wbuf, HDim, Dm);
    gemm_kernel<4><<<dim3(Dm / 128, Sq / 128, 2), 256, 0, stream>>>(
        ob_, wbuf, Sq, Dm, HDim, HDim / 2, nullptr, xnf, nullptr);

    // 5) cvt_prefill + W1 transpose (merged; wbuf dead after Wo-GEMM)
    cvtpf_w1t_kernel<<<2048 + (FF / 64) * (Dm / 64), 256, 0, stream>>>(
        xnf, b2, hbuf, out, W1, wbuf);

    // 6) FFN1 (+bias+gelu)
    gemm_kernel<2><<<dim3(FF / 128, Sq / 128, 1), 256, 0, stream>>>(
        hbuf, wbuf, Sq, FF, Dm, Dm, gb_, nullptr, b1);

    // 7) FFN2, split-K=2, atomic accumulate into prefilled out
    transpose_cvt_kernel<<<dim3(Dm / 64, FF / 64), 256, 0, stream>>>(W2, wbuf, FF, Dm);
    gemm_kernel<4><<<dim3(Dm / 128, Sq / 128, 2), 256, 0, stream>>>(
        gb_, wbuf, Sq, Dm, FF, FF / 2, nullptr, out, nullptr);
}

// Round 19
// 441.259 us; speedup vs baseline: 1.0903x; 1.0056x over previous
//
#include <hip/hip_runtime.h>
#include <hip/hip_bf16.h>

#define Sq 2048
#define Dm 2048
#define HDim 3072
#define QKVDim 9216
#define NH 24
#define DH 128
#define FF 8192
#define ATT_SCALE 0.08838834764831845f

using bf16 = __hip_bfloat16;
typedef __attribute__((ext_vector_type(8))) short bf16x8;
typedef __attribute__((ext_vector_type(4))) float f32x4;
typedef unsigned int u32;
typedef unsigned long long u64;
typedef __attribute__((ext_vector_type(4))) u32 u32x4;

__device__ __forceinline__ void gload_lds16(const void* g, void* l) {
    __builtin_amdgcn_global_load_lds(
        (const __attribute__((address_space(1))) void*)g,
        (__attribute__((address_space(3))) void*)l, 16, 0, 0);
}

// ---------------- merged: LayerNorm+RMSNorm rows  |  QKV weight transpose ------
__global__ __launch_bounds__(256) void ln_qkvt_kernel(
    const float* __restrict__ x, const float* __restrict__ g, const float* __restrict__ b,
    const float* __restrict__ ag, float* __restrict__ xnf, bf16* __restrict__ h,
    const float* __restrict__ Wq, const float* __restrict__ Wk, const float* __restrict__ Wv,
    bf16* __restrict__ Wt)
{
    union SmemU {
        float red[12];
        float tile[64][65];
    };
    __shared__ SmemU sm;
    int bid = blockIdx.x;
    int t = threadIdx.x;

    if (bid >= Sq) {
        int tb = bid - Sq;
        int z = tb / 1536, rr = tb % 1536;
        int bx = rr % 48, by = rr / 48;
        const float* W = z == 0 ? Wq : (z == 1 ? Wk : Wv);
        bf16* dst = Wt + (size_t)z * HDim * Dm;
        int n0 = bx * 64, k0 = by * 64;
        int lr = t >> 4, lc = (t & 15) * 4;
#pragma unroll
        for (int i = 0; i < 4; i++) {
            int r = lr + i * 16;
            f32x4 v = *reinterpret_cast<const f32x4*>(W + (size_t)(k0 + r) * HDim + n0 + lc);
            *reinterpret_cast<f32x4*>(&sm.tile[r][lc]) = v;
        }
        __syncthreads();
        int nr = t >> 3, kc = (t & 7) * 8;
#pragma unroll
        for (int i = 0; i < 2; i++) {
            int n = nr + i * 32;
            bf16 o8[8];
#pragma unroll
            for (int j = 0; j < 8; j++) o8[j] = __float2bfloat16(sm.tile[kc + j][n]);
            *reinterpret_cast<u32x4*>(dst + (size_t)(n0 + n) * Dm + k0 + kc) =
                *reinterpret_cast<const u32x4*>(o8);
        }
        return;
    }

    int row = bid;
    int lane = t & 63, wid = t >> 6;
    const float* xr = x + (size_t)row * Dm;

    float v[8];
    float sum = 0.f, ssq = 0.f;
#pragma unroll
    for (int i = 0; i < 8; i++) {
        float f = xr[t + 256 * i];
        v[i] = f; sum += f; ssq += f * f;
    }
#pragma unroll
    for (int off = 32; off > 0; off >>= 1) {
        sum += __shfl_down(sum, off);
        ssq += __shfl_down(ssq, off);
    }
    if (lane == 0) { sm.red[wid] = sum; sm.red[4 + wid] = ssq; }
    __syncthreads();
    sum = sm.red[0] + sm.red[1] + sm.red[2] + sm.red[3];
    ssq = sm.red[4] + sm.red[5] + sm.red[6] + sm.red[7];
    float mu = sum * (1.f / Dm);
    float var = ssq * (1.f / Dm) - mu * mu;
    float rstd = rsqrtf(var + 1e-5f);

    float xn[8];
    float s2 = 0.f;
#pragma unroll
    for (int i = 0; i < 8; i++) {
        int col = t + 256 * i;
        float xv = (v[i] - mu) * rstd * g[col] + b[col];
        xn[i] = xv;
        xnf[(size_t)row * Dm + col] = xv;
        s2 += xv * xv;
    }
#pragma unroll
    for (int off = 32; off > 0; off >>= 1) s2 += __shfl_down(s2, off);
    if (lane == 0) sm.red[8 + wid] = s2;
    __syncthreads();
    s2 = sm.red[8] + sm.red[9] + sm.red[10] + sm.red[11];
    float rms = rsqrtf(s2 * (1.f / Dm) + 1e-5f);
#pragma unroll
    for (int i = 0; i < 8; i++) {
        int col = t + 256 * i;
        h[(size_t)row * Dm + col] = __float2bfloat16(xn[i] * rms * ag[col]);
    }
}

// ---------------- transpose + fp32->bf16 convert: W[K][N] -> Wt[N][K] ----------------
__global__ __launch_bounds__(256) void transpose_cvt_kernel(
    const float* __restrict__ W, bf16* __restrict__ Wt, int K, int N)
{
    __shared__ float tile[64][65];
    int n0 = blockIdx.x * 64, k0 = blockIdx.y * 64;
    int t = threadIdx.x;
    int lr = t >> 4, lc = (t & 15) * 4;
#pragma unroll
    for (int i = 0; i < 4; i++) {
        int r = lr + i * 16;
        f32x4 v = *reinterpret_cast<const f32x4*>(W + (size_t)(k0 + r) * N + n0 + lc);
        *reinterpret_cast<f32x4*>(&tile[r][lc]) = v;
    }
    __syncthreads();
    int nr = t >> 3, kc = (t & 7) * 8;
#pragma unroll
    for (int i = 0; i < 2; i++) {
        int n = nr + i * 32;
        bf16 o8[8];
#pragma unroll
        for (int j = 0; j < 8; j++) o8[j] = __float2bfloat16(tile[kc + j][n]);
        *reinterpret_cast<u32x4*>(Wt + (size_t)(n0 + n) * K + k0 + kc) =
            *reinterpret_cast<const u32x4*>(o8);
    }
}

// ---------------- merged: cvt_prefill | W1 transpose ----------------
__global__ __launch_bounds__(256) void cvtpf_w1t_kernel(
    const float* __restrict__ xnf, const float* __restrict__ bias,
    bf16* __restrict__ hb, float* __restrict__ o,
    const float* __restrict__ W1, bf16* __restrict__ Wt)
{
    __shared__ float tile[64][65];
    int bid = blockIdx.x;
    int t = threadIdx.x;

    if (bid >= 2048) {
        int tb = bid - 2048;
        int bx = tb % (FF / 64), by = tb / (FF / 64);
        int n0 = bx * 64, k0 = by * 64;
        int lr = t >> 4, lc = (t & 15) * 4;
#pragma unroll
        for (int i = 0; i < 4; i++) {
            int r = lr + i * 16;
            f32x4 v = *reinterpret_cast<const f32x4*>(W1 + (size_t)(k0 + r) * FF + n0 + lc);
            *reinterpret_cast<f32x4*>(&tile[r][lc]) = v;
        }
        __syncthreads();
        int nr = t >> 3, kc = (t & 7) * 8;
#pragma unroll
        for (int i = 0; i < 2; i++) {
            int n = nr + i * 32;
            bf16 o8[8];
#pragma unroll
            for (int j = 0; j < 8; j++) o8[j] = __float2bfloat16(tile[kc + j][n]);
            *reinterpret_cast<u32x4*>(Wt + (size_t)(n0 + n) * Dm + k0 + kc) =
                *reinterpret_cast<const u32x4*>(o8);
        }
        return;
    }

    int i = (bid * 256 + t) * 8;
    int col = i % Dm;
    f32x4 a = *reinterpret_cast<const f32x4*>(xnf + i);
    f32x4 b = *reinterpret_cast<const f32x4*>(xnf + i + 4);
    bf16 r[8];
#pragma unroll
    for (int j = 0; j < 4; j++) { r[j] = __float2bfloat16(a[j]); r[4 + j] = __float2bfloat16(b[j]); }
    *reinterpret_cast<u32x4*>(hb + i) = *reinterpret_cast<const u32x4*>(r);
    f32x4 b0 = *reinterpret_cast<const f32x4*>(bias + col);
    f32x4 b1v = *reinterpret_cast<const f32x4*>(bias + col + 4);
    f32x4 o0 = {a[0] + b0[0], a[1] + b0[1], a[2] + b0[2], a[3] + b0[3]};
    f32x4 o1 = {b[0] + b1v[0], b[1] + b1v[1], b[2] + b1v[2], b[3] + b1v[3]};
    *reinterpret_cast<f32x4*>(o + i) = o0;
    *reinterpret_cast<f32x4*>(o + i + 4) = o1;
}

// ---------------- 128x128 bf16 MFMA GEMM (m97 structure, BK=64, swizzled) ------
// Panel-ordered block remap (PANEL=2): consecutive bids cover 2 N-panels x all
// M-panels -> ~9MB reuse window (~3MB/XCD-L2 under round-robin dispatch).
// EPI 0: Cb = bf16(acc);  EPI 2: Cb = bf16(gelu(acc+bias));  EPI 4: atomicAdd(Cf, acc)
template <int EPI>
__global__ __launch_bounds__(256, 4) void gemm_kernel(
    const bf16* __restrict__ A, const bf16* __restrict__ Bt,
    int M, int N, int K, int Ksplit,
    bf16* Cb, float* Cf, const float* __restrict__ bias)
{
    __shared__ __align__(16) bf16 As[128 * 64];
    __shared__ __align__(16) bf16 Bs[128 * 64];

    // serpentine panel remap over (x,y) grid, panel width 2 in x
    int gx = gridDim.x, gy = gridDim.y;
    int bid = blockIdx.y * gx + blockIdx.x;
    int np = gx >> 1;                      // panels (gx even for all our shapes)
    int panel = bid / (2 * gy), wi = bid % (2 * gy);
    int bx, by;
    if (panel < np) { bx = panel * 2 + (wi & 1); by = wi >> 1; }
    else            { bx = blockIdx.x; by = blockIdx.y; }   // safety (never taken)

    int m0 = by * 128, n0 = bx * 128;
    int kbeg = blockIdx.z * Ksplit, kend = kbeg + Ksplit;
    int tid = threadIdx.x;
    int lane = tid & 63, w = tid >> 6;
    int wr = w >> 1, wc = w & 1;
    int l15 = lane & 15, lhi = lane >> 4;

    int srow = lane >> 3;
    int scol = ((lane & 7) ^ (lane >> 3)) * 8;

    const f32x4 zero4 = {0.f, 0.f, 0.f, 0.f};
    f32x4 acc[4][4];
#pragma unroll
    for (int m = 0; m < 4; m++)
#pragma unroll
        for (int n = 0; n < 4; n++) acc[m][n] = zero4;

    for (int k0 = kbeg; k0 < kend; k0 += 64) {
        __syncthreads();
#pragma unroll
        for (int c = 0; c < 4; c++) {
            int row = w * 32 + c * 8 + srow;
            gload_lds16(A + (size_t)(m0 + row) * K + k0 + scol,
                        (char*)As + w * 4096 + c * 1024);
            gload_lds16(Bt + (size_t)(n0 + row) * K + k0 + scol,
                        (char*)Bs + w * 4096 + c * 1024);
        }
        __syncthreads();
#pragma unroll
        for (int ks = 0; ks < 2; ks++) {
            bf16x8 af[4], bfr[4];
#pragma unroll
            for (int m = 0; m < 4; m++) {
                int r = wr * 64 + m * 16 + l15;
                af[m] = *reinterpret_cast<const bf16x8*>(
                    &As[r * 64 + (((ks << 2) + lhi) ^ (r & 7)) * 8]);
            }
#pragma unroll
            for (int n = 0; n < 4; n++) {
                int r = wc * 64 + n * 16 + l15;
                bfr[n] = *reinterpret_cast<const bf16x8*>(
                    &Bs[r * 64 + (((ks << 2) + lhi) ^ (r & 7)) * 8]);
            }
#pragma unroll
            for (int m = 0; m < 4; m++)
#pragma unroll
                for (int n = 0; n < 4; n++)
                    acc[m][n] = __builtin_amdgcn_mfma_f32_16x16x32_bf16(af[m], bfr[n], acc[m][n], 0, 0, 0);
        }
    }

#pragma unroll
    for (int m = 0; m < 4; m++) {
        int row = m0 + wr * 64 + m * 16 + lhi * 4;
#pragma unroll
        for (int n = 0; n < 4; n++) {
            int col = n0 + wc * 64 + n * 16 + l15;
#pragma unroll
            for (int j = 0; j < 4; j++) {
                float vv = acc[m][n][j];
                size_t idx = (size_t)(row + j) * N + col;
                if (EPI == 0) {
                    Cb[idx] = __float2bfloat16(vv);
                } else if (EPI == 2) {
                    float o = vv + bias[col];
                    float u = 1.5957691216057308f * (o + 0.044715f * o * o * o);
                    Cb[idx] = __float2bfloat16(o / (1.0f + __expf(-u)));
                } else {
                    atomicAdd(&Cf[idx], vv);
                }
            }
        }
    }
}

// ---------------- flash-style causal attention, 8-wave QBLK=128 (r15 version) --
__global__ __launch_bounds__(512) void attn_kernel(
    const bf16* __restrict__ qkv, bf16* __restrict__ o)
{
    __shared__ __align__(16) bf16 KsF[2][64 * 128];
    __shared__ __align__(16) bf16 VtF[128 * 72];
    __shared__ __align__(16) bf16 Pl[8][16][76];
    int rank = blockIdx.x;
    int qb = (Sq / 128 - 1) - rank / NH;
    int head = rank % NH;
    const bf16* q = qkv + head * DH;
    const bf16* k = qkv + HDim + head * DH;
    const bf16* v = qkv + 2 * HDim + head * DH;
    int tid = threadIdx.x, lane = tid & 63, w = tid >> 6;
    int l15 = lane & 15, lhi = lane >> 4;
    int qrow0 = qb * 128 + w * 16;

    bf16x8 aq[4];
    const bf16* qbase = q + (size_t)(qrow0 + l15) * QKVDim;
#pragma unroll
    for (int kk = 0; kk < 4; kk++)
        aq[kk] = *reinterpret_cast<const bf16x8*>(qbase + kk * 32 + lhi * 8);

    bf16x8 vones;
#pragma unroll
    for (int j = 0; j < 8; j++) vones[j] = (short)0x3F80;

    int vkv = lhi * 2 + (w & 1) + (w >> 1) * 8;
    int vd0 = l15 * 8;
    int vxr = l15 & 7;
    const bf16* vbase = v + (size_t)vkv * QKVDim + vd0;

    const f32x4 zero4 = {0.f, 0.f, 0.f, 0.f};
    f32x4 acc_o[8];
#pragma unroll
    for (int db = 0; db < 8; db++) acc_o[db] = zero4;
    f32x4 acc_l = zero4;
    float mrow[4];
#pragma unroll
    for (int r = 0; r < 4; r++) mrow[r] = -1e30f;

    int nt = 2 * qb + 2;

    {
#pragma unroll
        for (int c = 0; c < 2; c++) {
            int row = w * 8 + c * 4 + lhi;
            int cb = l15 ^ (row & 7);
            gload_lds16(k + (size_t)row * QKVDim + cb * 8,
                        (char*)&KsF[0][0] + w * 2048 + c * 1024);
        }
#pragma unroll
        for (int i = 0; i < 2; i++) {
            int kv = vkv + i * 32;
            bf16x8 vv = *reinterpret_cast<const bf16x8*>(vbase + (size_t)(i * 32) * QKVDim);
            int vb = kv >> 3, kr = kv & 7;
#pragma unroll
            for (int j = 0; j < 8; j++)
                VtF[(vd0 + j) * 72 + ((vb ^ vxr) << 3) + kr] = ((const bf16*)&vv)[j];
        }
        __syncthreads();
    }

    for (int kb = 0; kb < nt; kb++) {
        int kv0 = kb * 64;
        int p = kb & 1;
        bf16x8 vreg[2];
        bool pref = (kb + 1 < nt);
        if (pref) {
            int nv0 = kv0 + 64;
#pragma unroll
            for (int c = 0; c < 2; c++) {
                int row = w * 8 + c * 4 + lhi;
                int cb = l15 ^ (row & 7);
                gload_lds16(k + (size_t)(nv0 + row) * QKVDim + cb * 8,
                            (char*)&KsF[p ^ 1][0] + w * 2048 + c * 1024);
            }
#pragma unroll
            for (int i = 0; i < 2; i++)
                vreg[i] = *reinterpret_cast<const bf16x8*>(
                    vbase + (size_t)(nv0 + i * 32) * QKVDim);
        }

        bool active = (kv0 <= qrow0 + 15);
        if (active) {
            f32x4 sacc[4];
            __builtin_amdgcn_s_setprio(1);
#pragma unroll
            for (int nb = 0; nb < 4; nb++) {
                sacc[nb] = zero4;
                int krow = nb * 16 + l15;
#pragma unroll
                for (int kk = 0; kk < 4; kk++) {
                    const char* kp = (const char*)&KsF[p][0] + krow * 256 +
                                     ((kk * 64 + lhi * 16) ^ ((krow & 7) << 4));
                    bf16x8 bk = *reinterpret_cast<const bf16x8*>(kp);
                    sacc[nb] = __builtin_amdgcn_mfma_f32_16x16x32_bf16(aq[kk], bk, sacc[nb], 0, 0, 0);
                }
            }
            __builtin_amdgcn_s_setprio(0);

            bool msk = (kv0 + 63 > qrow0);
            float sv[4][4];
            float pm[4];
#pragma unroll
            for (int r = 0; r < 4; r++) pm[r] = -1e30f;
#pragma unroll
            for (int nb = 0; nb < 4; nb++) {
                int kvc = kv0 + nb * 16 + l15;
#pragma unroll
                for (int r = 0; r < 4; r++) {
                    int qr = qrow0 + lhi * 4 + r;
                    float s = sacc[nb][r] * ATT_SCALE;
                    if (msk && kvc > qr) s = -1e30f;
                    sv[nb][r] = s;
                    pm[r] = fmaxf(pm[r], s);
                }
            }
#pragma unroll
            for (int off = 1; off < 16; off <<= 1)
#pragma unroll
                for (int r = 0; r < 4; r++)
                    pm[r] = fmaxf(pm[r], __shfl_xor(pm[r], off));

            float nm[4];
            bool need = false;
#pragma unroll
            for (int r = 0; r < 4; r++) {
                nm[r] = fmaxf(mrow[r], pm[r]);
                need = need || (pm[r] > mrow[r] + 8.f);
            }
            if (__any(need)) {
#pragma unroll
                for (int r = 0; r < 4; r++) {
                    float sc = __expf(mrow[r] - nm[r]);
                    mrow[r] = nm[r];
                    acc_l[r] *= sc;
#pragma unroll
                    for (int db = 0; db < 8; db++) acc_o[db][r] *= sc;
                }
            }

#pragma unroll
            for (int nb = 0; nb < 4; nb++)
#pragma unroll
                for (int r = 0; r < 4; r++)
                    sv[nb][r] = __expf(sv[nb][r] - mrow[r]);

#pragma unroll
            for (int nb = 0; nb < 4; nb++)
#pragma unroll
                for (int r = 0; r < 4; r++)
                    Pl[w][lhi * 4 + r][nb * 16 + l15] = __float2bfloat16(sv[nb][r]);

            __builtin_amdgcn_s_setprio(1);
#pragma unroll
            for (int ks = 0; ks < 2; ks++) {
                bf16x8 ap = *reinterpret_cast<const bf16x8*>(&Pl[w][l15][ks * 32 + lhi * 8]);
                acc_l = __builtin_amdgcn_mfma_f32_16x16x32_bf16(ap, vones, acc_l, 0, 0, 0);
#pragma unroll
                for (int db = 0; db < 8; db++) {
                    int dv = db * 16 + l15;
                    int blk = (ks * 4 + lhi) ^ ((dv >> 3) & 7);
                    bf16x8 bv = *reinterpret_cast<const bf16x8*>(&VtF[dv * 72 + blk * 8]);
                    acc_o[db] = __builtin_amdgcn_mfma_f32_16x16x32_bf16(ap, bv, acc_o[db], 0, 0, 0);
                }
            }
            __builtin_amdgcn_s_setprio(0);
        }

        __syncthreads();
        if (pref) {
#pragma unroll
            for (int i = 0; i < 2; i++) {
                int kv = vkv + i * 32;
                int vb = kv >> 3, kr = kv & 7;
#pragma unroll
                for (int j = 0; j < 8; j++)
                    VtF[(vd0 + j) * 72 + ((vb ^ vxr) << 3) + kr] = ((const bf16*)&vreg[i])[j];
            }
        }
        __syncthreads();
    }

#pragma unroll
    for (int db = 0; db < 8; db++)
#pragma unroll
        for (int r = 0; r < 4; r++) {
            int qr = qrow0 + lhi * 4 + r;
            float val = acc_o[db][r] / acc_l[r];
            o[(size_t)qr * HDim + head * DH + db * 16 + l15] = __float2bfloat16(val);
        }
}

// ---------------- host launch ----------------
extern "C" void kernel_launch(void* const* d_in, const int* in_sizes, int n_in,
                              void* d_out, int out_size, void* d_ws, size_t ws_size,
                              hipStream_t stream)
{
    const float* x     = (const float*)d_in[0];
    const float* ln_g  = (const float*)d_in[1];
    const float* ln_b  = (const float*)d_in[2];
    const float* attng = (const float*)d_in[3];
    const float* Wq    = (const float*)d_in[4];
    const float* Wk    = (const float*)d_in[5];
    const float* Wv    = (const float*)d_in[6];
    const float* Wo    = (const float*)d_in[7];
    const float* W1    = (const float*)d_in[8];
    const float* b1    = (const float*)d_in[9];
    const float* W2    = (const float*)d_in[10];
    const float* b2    = (const float*)d_in[11];
    float* out = (float*)d_out;
    char* ws = (char*)d_ws;

    bf16*  wbuf = (bf16*)(ws + 0);
    float* xnf  = (float*)(ws + 39845888);
    bf16*  hbuf = (bf16*)(ws + 56623104);
    bf16*  qkv  = (bf16*)(ws + 65011712);
    bf16*  ob_  = (bf16*)(ws + 102760448);
    bf16*  gb_  = qkv;

    ln_qkvt_kernel<<<Sq + 3 * 1536, 256, 0, stream>>>(
        x, ln_g, ln_b, attng, xnf, hbuf, Wq, Wk, Wv, wbuf);

    gemm_kernel<0><<<dim3(QKVDim / 128, Sq / 128, 1), 256, 0, stream>>>(
        hbuf, wbuf, Sq, QKVDim, Dm, Dm, qkv, nullptr, nullptr);

    attn_kernel<<<dim3(NH * Sq / 128), 512, 0, stream>>>(qkv, ob_);

    transpose_cvt_kernel<<<dim3(Dm / 64, HDim / 64), 256, 0, stream>>>(Wo, wbuf, HDim, Dm);
    gemm_kernel<4><<<dim3(Dm / 128, Sq / 128, 2), 256, 0, stream>>>(
        ob_, wbuf, Sq, Dm, HDim, HDim / 2, nullptr, xnf, nullptr);

    cvtpf_w1t_kernel<<<2048 + (FF / 64) * (Dm / 64), 256, 0, stream>>>(
        xnf, b2, hbuf, out, W1, wbuf);

    gemm_kernel<2><<<dim3(FF / 128, Sq / 128, 1), 256, 0, stream>>>(
        hbuf, wbuf, Sq, FF, Dm, Dm, gb_, nullptr, b1);

    transpose_cvt_kernel<<<dim3(Dm / 64, FF / 64), 256, 0, stream>>>(W2, wbuf, FF, Dm);
    gemm_kernel<4><<<dim3(Dm / 128, Sq / 128, 2), 256, 0, stream>>>(
        gb_, wbuf, Sq, Dm, FF, FF / 2, nullptr, out, nullptr);
}